// Round 6
// baseline (976.535 us; speedup 1.0000x reference)
//
#include <hip/hip_runtime.h>

#define N_NODES 100000
#define N_EDGES 1600000
#define M_PAD   100096   // 1564 * 64
#define BCAP    64       // bucket capacity per node (Poisson(16): P(>=64) ~ 1e-20)
#define EBLK    782      // edge-role blocks inside fused_mlp
#define X_REAL 51200000L          // N_NODES*512
#define X_PAD  ((long)M_PAD*512)  // divisible by 2048

typedef __bf16 bf16x8 __attribute__((ext_vector_type(8)));
typedef float  f32x4  __attribute__((ext_vector_type(4)));
typedef unsigned short u16x8 __attribute__((ext_vector_type(8)));

__device__ __forceinline__ unsigned short f2bf(float f) {
  union { float f; unsigned u; } x; x.f = f;
  unsigned r = (x.u + 0x7FFFu + ((x.u >> 16) & 1u)) >> 16;
  return (unsigned short)r;
}

__device__ __forceinline__ float bf2f(unsigned short h) {
  union { unsigned u; float f; } x; x.u = ((unsigned)h) << 16;
  return x.f;
}

__device__ __forceinline__ void async_copy16(const void* g, void* l) {
  __builtin_amdgcn_global_load_lds((__attribute__((address_space(1))) void*)g,
                                   (__attribute__((address_space(3))) void*)l,
                                   16, 0, 0);
}

// XOR-swizzled u16 index into an LDS tile with 1024 B row stride (64x512 bf16).
// Breaks the 16-way same-bank alignment of 128B-multiple row strides (G4).
__device__ __forceinline__ int swz1(int row, int col) {
  return ((row * 1024 + col * 2) ^ ((row & 7) << 4)) >> 1;
}
// Same for 512 B row stride (64x256 bf16).
__device__ __forceinline__ int swz2(int row, int col) {
  return ((row * 512 + col * 2) ^ ((row & 7) << 4)) >> 1;
}

// ---------------- prep kernels ----------------

__global__ void cvt_x_kernel(const float* __restrict__ x, unsigned short* __restrict__ xb) {
  long e = ((long)blockIdx.x * 256 + threadIdx.x) * 8;
  u16x8 o;
  if (e < X_REAL) {
    float4 f0 = *(const float4*)(x + e);
    float4 f1 = *(const float4*)(x + e + 4);
    o[0] = f2bf(f0.x); o[1] = f2bf(f0.y); o[2] = f2bf(f0.z); o[3] = f2bf(f0.w);
    o[4] = f2bf(f1.x); o[5] = f2bf(f1.y); o[6] = f2bf(f1.z); o[7] = f2bf(f1.w);
  } else {
    o = (u16x8)0;
  }
  *(u16x8*)(xb + e) = o;
}

// W [K][N] fp32 -> Wt [Npad][K] bf16 (rows >= N zero-filled)
__global__ void cvt_wt_kernel(const float* __restrict__ W, unsigned short* __restrict__ Wt,
                              int K, int N, int Npad) {
  int idx = blockIdx.x * 256 + threadIdx.x;
  if (idx >= Npad * K) return;
  int n = idx / K, k = idx % K;
  Wt[idx] = (n < N) ? f2bf(W[(long)k * N + n]) : (unsigned short)0;
}

// W [64][N] fp32 -> Wt [64][128] bf16 with K duplicated: Wt[n][k] = W[k&63][n]
__global__ void cvt_wt_dup_kernel(const float* __restrict__ W, unsigned short* __restrict__ Wt,
                                  int N) {
  int idx = blockIdx.x * 256 + threadIdx.x;
  if (idx >= 64 * 128) return;
  int n = idx >> 7, k = idx & 127;
  Wt[idx] = (n < N) ? f2bf(W[(long)(k & 63) * N + n]) : (unsigned short)0;
}

__global__ void norms_kernel(const int* __restrict__ hist,
                             float* __restrict__ nsrc, float* __restrict__ ndst) {
  int i = blockIdx.x * 256 + threadIdx.x;
  if (i >= M_PAD) return;
  if (i < N_NODES) {
    nsrc[i] = rsqrtf(fmaxf((float)hist[N_NODES + i], 1.f));  // deg_out
    ndst[i] = rsqrtf(fmaxf((float)hist[i], 1.f));            // deg_in
  } else {
    nsrc[i] = 1.f;
  }
}

// ---------------- fused MLP: u0 = relu(relu(relu(x@W1+b1)@W2+b2)@W3+b3) --------------
// One block = 64 rows end-to-end; h1 (64x512) and h2 (64x256) live only in LDS (bf16,
// XOR-swizzled). W1/W2/W3 are L2-resident and streamed per block. Eliminates the h1/h2
// HBM round-trips (306 MB). blockIdx.x==1 blocks run the edge-bucket/histogram role.
// NOTE: no ×nsrc here (hist is built in this same dispatch); the first aggregate
// applies nsrc[s] per gathered neighbor instead.
__launch_bounds__(512)
__global__ void fused_mlp(const unsigned short* __restrict__ xb,
                          const unsigned short* __restrict__ W1t,   // [512][512]
                          const unsigned short* __restrict__ W2t,   // [256][512]
                          const unsigned short* __restrict__ W3t,   // [64][256]
                          const float* __restrict__ b1,
                          const float* __restrict__ b2,
                          const float* __restrict__ b3,
                          unsigned short* __restrict__ u0,          // [M_PAD][64] bf16
                          const int* __restrict__ esrc, const int* __restrict__ edst,
                          int* __restrict__ hist, int* __restrict__ bucket) {
  if (blockIdx.x == 1) {  // ---- edge role ----
    if (blockIdx.y >= EBLK) return;
    const int S = EBLK * 512;
    int e = blockIdx.y * 512 + (int)threadIdx.x;
    for (; e + 3 * S < N_EDGES; e += 4 * S) {
      int s0 = esrc[e],         d0 = edst[e];
      int s1 = esrc[e + S],     d1 = edst[e + S];
      int s2 = esrc[e + 2 * S], d2 = edst[e + 2 * S];
      int s3 = esrc[e + 3 * S], d3 = edst[e + 3 * S];
      atomicAdd(&hist[N_NODES + s0], 1);
      atomicAdd(&hist[N_NODES + s1], 1);
      atomicAdd(&hist[N_NODES + s2], 1);
      atomicAdd(&hist[N_NODES + s3], 1);
      int p0 = atomicAdd(&hist[d0], 1);
      int p1 = atomicAdd(&hist[d1], 1);
      int p2 = atomicAdd(&hist[d2], 1);
      int p3 = atomicAdd(&hist[d3], 1);
      if (p0 < BCAP) bucket[(size_t)d0 * BCAP + p0] = s0;
      if (p1 < BCAP) bucket[(size_t)d1 * BCAP + p1] = s1;
      if (p2 < BCAP) bucket[(size_t)d2 * BCAP + p2] = s2;
      if (p3 < BCAP) bucket[(size_t)d3 * BCAP + p3] = s3;
    }
    for (; e < N_EDGES; e += S) {
      int s = esrc[e], d = edst[e];
      atomicAdd(&hist[N_NODES + s], 1);
      int p = atomicAdd(&hist[d], 1);
      if (p < BCAP) bucket[(size_t)d * BCAP + p] = s;
    }
    return;
  }
  // ---- GEMM role: 8 waves in 2(M)x4(N) ----
  __shared__ __align__(16) unsigned short Xs[64 * 64];    // 8 KB: x tile per k-step
  __shared__ __align__(16) unsigned short Wb[64 * 512];   // 64 KB: W1 tile -> h1 -> h2
  __shared__ __align__(16) unsigned short W2s[256 * 64];  // 32 KB: W2 tile / whole W3
  const int tid = threadIdx.x;
  const int wave = tid >> 6, lane = tid & 63;
  const int l15 = lane & 15, l4 = lane >> 4;
  const int wm0 = (wave >> 2) * 32;
  const int wnA = (wave & 3) * 128, wnB = (wave & 3) * 64, wnC = (wave & 3) * 16;
  const long rowBase = (long)blockIdx.y * 64;

  float b1c[8], b2c[4];
#pragma unroll
  for (int ni = 0; ni < 8; ++ni) b1c[ni] = b1[wnA + ni * 16 + l15];
#pragma unroll
  for (int ni = 0; ni < 4; ++ni) b2c[ni] = b2[wnB + ni * 16 + l15];
  const float b3c = b3[wnC + l15];

  // ===== step A: h1 = relu(x @ W1 + b1), 64x512, K=512 =====
  f32x4 acc1[2][8] = {};
  for (int k0 = 0; k0 < 512; k0 += 64) {
    {  // Xs: 512 chunks, exactly 1 per thread
      int r = tid >> 3, cc = (tid & 7) * 8;
      async_copy16(xb + (rowBase + r) * 512 + k0 + cc, &Xs[tid * 8]);
    }
#pragma unroll
    for (int c = tid; c < 4096; c += 512) {  // W1 tile: [512][64]
      int r = c >> 3, cc = (c & 7) * 8;
      async_copy16(W1t + (long)r * 512 + k0 + cc, &Wb[c * 8]);
    }
    __syncthreads();
#pragma unroll
    for (int kk = 0; kk < 64; kk += 32) {
      bf16x8 af[2], bfr[8];
#pragma unroll
      for (int mi = 0; mi < 2; ++mi)
        af[mi] = *(const bf16x8*)&Xs[(wm0 + mi * 16 + l15) * 64 + kk + l4 * 8];
#pragma unroll
      for (int ni = 0; ni < 8; ++ni)
        bfr[ni] = *(const bf16x8*)&Wb[(wnA + ni * 16 + l15) * 64 + kk + l4 * 8];
#pragma unroll
      for (int mi = 0; mi < 2; ++mi)
#pragma unroll
        for (int ni = 0; ni < 8; ++ni)
          acc1[mi][ni] = __builtin_amdgcn_mfma_f32_16x16x32_bf16(af[mi], bfr[ni], acc1[mi][ni], 0, 0, 0);
    }
    __syncthreads();
  }
  // h1 tile -> Wb (swizzled); Wb's W1 contents dead after the loop's trailing barrier
#pragma unroll
  for (int mi = 0; mi < 2; ++mi)
#pragma unroll
    for (int ni = 0; ni < 8; ++ni)
#pragma unroll
      for (int r = 0; r < 4; ++r) {
        int row = wm0 + mi * 16 + l4 * 4 + r;
        int col = wnA + ni * 16 + l15;
        Wb[swz1(row, col)] = f2bf(fmaxf(acc1[mi][ni][r] + b1c[ni], 0.f));
      }
  __syncthreads();

  // ===== step B: h2 = relu(h1 @ W2 + b2), 64x256, K=512 =====
  f32x4 acc2[2][4] = {};
  for (int k0 = 0; k0 < 512; k0 += 64) {
#pragma unroll
    for (int c = tid; c < 2048; c += 512) {  // W2 tile: [256][64]
      int r = c >> 3, cc = (c & 7) * 8;
      async_copy16(W2t + (long)r * 512 + k0 + cc, &W2s[c * 8]);
    }
    __syncthreads();
#pragma unroll
    for (int kk = 0; kk < 64; kk += 32) {
      bf16x8 af[2], bfr[4];
#pragma unroll
      for (int mi = 0; mi < 2; ++mi)
        af[mi] = *(const bf16x8*)&Wb[swz1(wm0 + mi * 16 + l15, k0 + kk + l4 * 8)];
#pragma unroll
      for (int ni = 0; ni < 4; ++ni)
        bfr[ni] = *(const bf16x8*)&W2s[(wnB + ni * 16 + l15) * 64 + kk + l4 * 8];
#pragma unroll
      for (int mi = 0; mi < 2; ++mi)
#pragma unroll
        for (int ni = 0; ni < 4; ++ni)
          acc2[mi][ni] = __builtin_amdgcn_mfma_f32_16x16x32_bf16(af[mi], bfr[ni], acc2[mi][ni], 0, 0, 0);
    }
    __syncthreads();
  }
  // h2 tile -> Wb[0:32KB] (swizzled); h1 dead after trailing barrier
#pragma unroll
  for (int mi = 0; mi < 2; ++mi)
#pragma unroll
    for (int ni = 0; ni < 4; ++ni)
#pragma unroll
      for (int r = 0; r < 4; ++r) {
        int row = wm0 + mi * 16 + l4 * 4 + r;
        int col = wnB + ni * 16 + l15;
        Wb[swz2(row, col)] = f2bf(fmaxf(acc2[mi][ni][r] + b2c[ni], 0.f));
      }
  __syncthreads();

  // ===== step C: u0 = relu(h2 @ W3 + b3), 64x64, K=256 =====
#pragma unroll
  for (int c = tid; c < 2048; c += 512)  // whole W3t [64][256], linear
    async_copy16(W3t + c * 8, &W2s[c * 8]);
  __syncthreads();
  f32x4 acc3[2] = {};
#pragma unroll
  for (int kk = 0; kk < 256; kk += 32) {
    bf16x8 af[2], bfr;
    bfr = *(const bf16x8*)&W2s[(wnC + l15) * 256 + kk + l4 * 8];
#pragma unroll
    for (int mi = 0; mi < 2; ++mi) {
      af[mi] = *(const bf16x8*)&Wb[swz2(wm0 + mi * 16 + l15, kk + l4 * 8)];
      acc3[mi] = __builtin_amdgcn_mfma_f32_16x16x32_bf16(af[mi], bfr, acc3[mi], 0, 0, 0);
    }
  }
#pragma unroll
  for (int mi = 0; mi < 2; ++mi)
#pragma unroll
    for (int r = 0; r < 4; ++r) {
      long row = rowBase + wm0 + mi * 16 + l4 * 4 + r;
      int col = wnC + l15;
      u0[row * 64 + col] = f2bf(fmaxf(acc3[mi][r] + b3c, 0.f));
    }
}

// ---------------- GEMM for the GCN za layers (unchanged from round 5) --------------
// EPI 1: bf16( relu(acc + bias[col]) * rowscale[row] )
// EPI 4: f32 relu(acc + bias[col]) -> out[row][col], row<N_NODES, col<40 (final)
template <int BM, int BN, int BK, int EPI, int TPB>
__launch_bounds__(TPB)
__global__ void gemm_bt(const unsigned short* __restrict__ A,
                        const unsigned short* __restrict__ Bt,
                        const float* __restrict__ bias,
                        const float* __restrict__ rowscale,
                        void* __restrict__ C, int K, int Nfull) {
  constexpr int WAVES = TPB / 64;
  constexpr int WAVES_M = 2, WAVES_N = WAVES / 2;
  constexpr int WM = BM / WAVES_M, WN = BN / WAVES_N;
  constexpr int MI = WM / 16, NI = WN / 16;
  __shared__ __align__(16) unsigned short As[BM * BK];
  __shared__ __align__(16) unsigned short Bs[BN * BK];
  const int tid = threadIdx.x;
  const int wave = tid >> 6, lane = tid & 63;
  const int wm0 = (wave / WAVES_N) * WM, wn0 = (wave % WAVES_N) * WN;
  const long rowBase = (long)blockIdx.y * BM;
  const int colBase = blockIdx.x * BN;
  const unsigned short* Ab = A + rowBase * K;
  const unsigned short* Bb = Bt + (long)colBase * K;
  f32x4 acc[MI][NI] = {};
  constexpr int ACH = BM * BK / 8;
  constexpr int BCH = BN * BK / 8;
  for (int k0 = 0; k0 < K; k0 += BK) {
#pragma unroll
    for (int c = tid; c < ACH; c += TPB) {
      int r = (c * 8) / BK, cc = (c * 8) % BK;
      async_copy16(Ab + (long)r * K + k0 + cc, &As[c * 8]);
    }
#pragma unroll
    for (int c = tid; c < BCH; c += TPB) {
      int r = (c * 8) / BK, cc = (c * 8) % BK;
      async_copy16(Bb + (long)r * K + k0 + cc, &Bs[c * 8]);
    }
    __syncthreads();
#pragma unroll
    for (int kk = 0; kk < BK; kk += 32) {
      bf16x8 af[MI], bfr[NI];
#pragma unroll
      for (int mi = 0; mi < MI; ++mi)
        af[mi] = *(const bf16x8*)&As[(wm0 + mi * 16 + (lane & 15)) * BK + kk + (lane >> 4) * 8];
#pragma unroll
      for (int ni = 0; ni < NI; ++ni)
        bfr[ni] = *(const bf16x8*)&Bs[(wn0 + ni * 16 + (lane & 15)) * BK + kk + (lane >> 4) * 8];
#pragma unroll
      for (int mi = 0; mi < MI; ++mi)
#pragma unroll
        for (int ni = 0; ni < NI; ++ni)
          acc[mi][ni] = __builtin_amdgcn_mfma_f32_16x16x32_bf16(af[mi], bfr[ni], acc[mi][ni], 0, 0, 0);
    }
    __syncthreads();
  }
  const int q = lane >> 4, c15 = lane & 15;
#pragma unroll
  for (int mi = 0; mi < MI; ++mi) {
#pragma unroll
    for (int ni = 0; ni < NI; ++ni) {
#pragma unroll
      for (int r = 0; r < 4; ++r) {
        long row = rowBase + wm0 + mi * 16 + q * 4 + r;
        int col = colBase + wn0 + ni * 16 + c15;
        float v = acc[mi][ni][r];
        if constexpr (EPI == 1) {
          v = fmaxf(v + bias[col], 0.f) * rowscale[row];
          ((unsigned short*)C)[row * Nfull + col] = f2bf(v);
        } else {  // EPI == 4
          float bv = (col < 40) ? bias[col] : 0.f;
          float vv = fmaxf(v + bv, 0.f);
          if (row < N_NODES && col < 40)
            ((float*)C)[row * 40 + col] = vv;
        }
      }
    }
  }
}

// ---------------- aggregation over bf16 u-rows ------------------------------------
// za[node][0:64]  = bf16_hi( ndst[node] * sum_s w_s * u[s][:] ), w_s = nsrc[s] if
// SCALE_SRC (first GCN layer; u0 lacks the nsrc factor) else 1.
// za[node][64:128]= bf16_lo( residual )   (K=128 GEMM vs dup-W gives ~f32)
__device__ __forceinline__ void agg_body(const unsigned short* __restrict__ u,
                                         const int* __restrict__ bucket,
                                         const int* __restrict__ cnt,
                                         const float* __restrict__ ndst,
                                         const float* __restrict__ nsrc,
                                         unsigned short* __restrict__ za,
                                         const int SCALE_SRC) {
  const int node = blockIdx.x * 4 + (threadIdx.x >> 6);
  const int lane = threadIdx.x & 63;
  const int r8 = lane >> 3;
  const int c8 = (lane & 7) * 8;
  float a0 = 0.f, a1 = 0.f, a2 = 0.f, a3 = 0.f, a4 = 0.f, a5 = 0.f, a6 = 0.f, a7 = 0.f;
  int n = 0;
  if (node < N_NODES) n = min(cnt[node], BCAP);
  const int* bk = bucket + (size_t)node * BCAP;
#pragma unroll 2
  for (int i = r8; i < n; i += 8) {
    int s = bk[i];
    float w = SCALE_SRC ? nsrc[s] : 1.f;
    u16x8 v = *(const u16x8*)(u + (size_t)s * 64 + c8);
    a0 += w * bf2f(v[0]); a1 += w * bf2f(v[1]); a2 += w * bf2f(v[2]); a3 += w * bf2f(v[3]);
    a4 += w * bf2f(v[4]); a5 += w * bf2f(v[5]); a6 += w * bf2f(v[6]); a7 += w * bf2f(v[7]);
  }
#pragma unroll
  for (int m = 8; m <= 32; m <<= 1) {
    a0 += __shfl_xor(a0, m); a1 += __shfl_xor(a1, m);
    a2 += __shfl_xor(a2, m); a3 += __shfl_xor(a3, m);
    a4 += __shfl_xor(a4, m); a5 += __shfl_xor(a5, m);
    a6 += __shfl_xor(a6, m); a7 += __shfl_xor(a7, m);
  }
  if (r8 == 0) {
    float nd = (node < N_NODES) ? ndst[node] : 0.f;
    float vv[8] = {nd * a0, nd * a1, nd * a2, nd * a3, nd * a4, nd * a5, nd * a6, nd * a7};
    u16x8 H, L;
#pragma unroll
    for (int t = 0; t < 8; ++t) {
      unsigned short h = f2bf(vv[t]);
      H[t] = h;
      L[t] = f2bf(vv[t] - bf2f(h));
    }
    *(u16x8*)(za + (size_t)node * 128 + c8) = H;
    *(u16x8*)(za + (size_t)node * 128 + 64 + c8) = L;
  }
}

template <int SCALE_SRC>
__global__ void agg_kernel(const unsigned short* __restrict__ u,
                           const int* __restrict__ bucket, const int* __restrict__ cnt,
                           const float* __restrict__ ndst, const float* __restrict__ nsrc,
                           unsigned short* __restrict__ za) {
  agg_body(u, bucket, cnt, ndst, nsrc, za, SCALE_SRC);
}

// ---------------- launch ----------------

extern "C" void kernel_launch(void* const* d_in, const int* in_sizes, int n_in,
                              void* d_out, int out_size, void* d_ws, size_t ws_size,
                              hipStream_t stream) {
  (void)in_sizes; (void)n_in; (void)out_size; (void)ws_size;
  const float* x   = (const float*)d_in[0];
  const int* esrc  = (const int*)d_in[1];
  const int* edst  = (const int*)d_in[2];
  const float* W1  = (const float*)d_in[3];  const float* b1  = (const float*)d_in[4];
  const float* W2  = (const float*)d_in[5];  const float* b2  = (const float*)d_in[6];
  const float* W3  = (const float*)d_in[7];  const float* b3  = (const float*)d_in[8];
  const float* Wg1 = (const float*)d_in[9];  const float* bg1 = (const float*)d_in[10];
  const float* Wg2 = (const float*)d_in[11]; const float* bg2 = (const float*)d_in[12];
  const float* Wg3 = (const float*)d_in[13]; const float* bg3 = (const float*)d_in[14];
  const float* Wg4 = (const float*)d_in[15]; const float* bg4 = (const float*)d_in[16];
  float* out = (float*)d_out;

  char* ws = (char*)d_ws;
  size_t off = 0;
  auto alloc = [&](size_t bytes) -> void* {
    void* p = ws + off;
    off += (bytes + 255) & ~(size_t)255;
    return p;
  };

  unsigned short* xb = (unsigned short*)alloc((size_t)M_PAD * 512 * 2);  // live through fused_mlp
  unsigned short* r1 = (unsigned short*)alloc((size_t)M_PAD * 512 * 2);  // U0|U1|za pool
  int*   bucket  = (int*)alloc((size_t)N_NODES * BCAP * 4);
  int*   hist    = (int*)alloc((size_t)2 * N_NODES * 4);
  float* nsrc    = (float*)alloc((size_t)M_PAD * 4);
  float* ndst    = (float*)alloc((size_t)N_NODES * 4);
  unsigned short* W1t  = (unsigned short*)alloc(512 * 512 * 2);
  unsigned short* W2t  = (unsigned short*)alloc(256 * 512 * 2);
  unsigned short* W3t  = (unsigned short*)alloc(64 * 256 * 2);
  unsigned short* Wg1t = (unsigned short*)alloc(64 * 128 * 2);   // dup-K layout
  unsigned short* Wg2t = (unsigned short*)alloc(64 * 128 * 2);
  unsigned short* Wg3t = (unsigned short*)alloc(64 * 128 * 2);
  unsigned short* Wg4t = (unsigned short*)alloc(64 * 128 * 2);

  unsigned short* U0 = r1;                                   // M_PAD*64 bf16
  unsigned short* U1 = r1 + (size_t)M_PAD * 64;              // M_PAD*64 bf16
  unsigned short* za = r1 + (size_t)M_PAD * 128;             // M_PAD*128 bf16

  // 1) zero both histograms
  hipMemsetAsync(hist, 0, (size_t)2 * N_NODES * 4, stream);

  // 2) x -> bf16 padded
  cvt_x_kernel<<<(int)(X_PAD / 8 / 256), 256, 0, stream>>>(x, xb);

  // 3) weights -> bf16 transposed [Npad][K]; GCN weights in dup-K [64][128]
  cvt_wt_kernel<<<(512 * 512 + 255) / 256, 256, 0, stream>>>(W1, W1t, 512, 512, 512);
  cvt_wt_kernel<<<(256 * 512 + 255) / 256, 256, 0, stream>>>(W2, W2t, 512, 256, 256);
  cvt_wt_kernel<<<(64 * 256 + 255) / 256, 256, 0, stream>>>(W3, W3t, 256, 64, 64);
  cvt_wt_dup_kernel<<<(64 * 128 + 255) / 256, 256, 0, stream>>>(Wg1, Wg1t, 64);
  cvt_wt_dup_kernel<<<(64 * 128 + 255) / 256, 256, 0, stream>>>(Wg2, Wg2t, 64);
  cvt_wt_dup_kernel<<<(64 * 128 + 255) / 256, 256, 0, stream>>>(Wg3, Wg3t, 64);
  cvt_wt_dup_kernel<<<(64 * 128 + 255) / 256, 256, 0, stream>>>(Wg4, Wg4t, 40);  // pad 40->64

  // 4) fused MLP (x -> u0raw, h1/h2 LDS-only) + edge-bucket build (x==1 role)
  fused_mlp<<<dim3(2, M_PAD / 64), 512, 0, stream>>>(
      xb, W1t, W2t, W3t, b1, b2, b3, U0, esrc, edst, hist, bucket);

  // 5) norms (hist complete after fused dispatch)
  norms_kernel<<<(M_PAD + 255) / 256, 256, 0, stream>>>(hist, nsrc, ndst);

  const int GY = M_PAD / 128;  // 782

  // 6) GCN layers: za = hi/lo(ndst * segsum(w*u)); u' = bf16(nsrc*relu(za@Wdup+b))
  //    first agg applies nsrc[s] per neighbor (u0raw lacks it).
  agg_kernel<1><<<M_PAD / 4, 256, 0, stream>>>(U0, bucket, hist, ndst, nsrc, za);
  gemm_bt<128, 64, 64, 1, 256><<<dim3(1, GY), 256, 0, stream>>>(
      za, Wg1t, bg1, nsrc, U1, 128, 64);

  agg_kernel<0><<<M_PAD / 4, 256, 0, stream>>>(U1, bucket, hist, ndst, nsrc, za);
  gemm_bt<128, 64, 64, 1, 256><<<dim3(1, GY), 256, 0, stream>>>(
      za, Wg2t, bg2, nsrc, U0, 128, 64);

  agg_kernel<0><<<M_PAD / 4, 256, 0, stream>>>(U0, bucket, hist, ndst, nsrc, za);
  gemm_bt<128, 64, 64, 1, 256><<<dim3(1, GY), 256, 0, stream>>>(
      za, Wg3t, bg3, nsrc, U1, 128, 64);

  agg_kernel<0><<<M_PAD / 4, 256, 0, stream>>>(U1, bucket, hist, ndst, nsrc, za);
  gemm_bt<128, 64, 64, 4, 256><<<dim3(1, GY), 256, 0, stream>>>(
      za, Wg4t, bg4, nullptr, out, 128, 64);
}

// Round 7
// 840.292 us; speedup vs baseline: 1.1621x; 1.1621x over previous
//
#include <hip/hip_runtime.h>

#define N_NODES 100000
#define N_EDGES 1600000
#define M_PAD   100096   // 782 * 128
#define BCAP    64       // bucket capacity per node (Poisson(16): P(>=64) ~ 1e-20)
#define X_REAL 51200000L          // N_NODES*512
#define X_PAD  ((long)M_PAD*512)  // 51249152, divisible by 2048

typedef __bf16 bf16x8 __attribute__((ext_vector_type(8)));
typedef float  f32x4  __attribute__((ext_vector_type(4)));
typedef unsigned short u16x8 __attribute__((ext_vector_type(8)));

__device__ __forceinline__ unsigned short f2bf(float f) {
  union { float f; unsigned u; } x; x.f = f;
  unsigned r = (x.u + 0x7FFFu + ((x.u >> 16) & 1u)) >> 16;
  return (unsigned short)r;
}

__device__ __forceinline__ float bf2f(unsigned short h) {
  union { unsigned u; float f; } x; x.u = ((unsigned)h) << 16;
  return x.f;
}

__device__ __forceinline__ void async_copy16(const void* g, void* l) {
  __builtin_amdgcn_global_load_lds((__attribute__((address_space(1))) void*)g,
                                   (__attribute__((address_space(3))) void*)l,
                                   16, 0, 0);
}

// ---------------- prep kernels ----------------

__global__ void cvt_x_kernel(const float* __restrict__ x, unsigned short* __restrict__ xb) {
  long e = ((long)blockIdx.x * 256 + threadIdx.x) * 8;   // grid sized exactly: X_PAD/8/256 blocks
  u16x8 o;
  if (e < X_REAL) {
    float4 f0 = *(const float4*)(x + e);
    float4 f1 = *(const float4*)(x + e + 4);
    o[0] = f2bf(f0.x); o[1] = f2bf(f0.y); o[2] = f2bf(f0.z); o[3] = f2bf(f0.w);
    o[4] = f2bf(f1.x); o[5] = f2bf(f1.y); o[6] = f2bf(f1.z); o[7] = f2bf(f1.w);
  } else {
    o = (u16x8)0;
  }
  *(u16x8*)(xb + e) = o;
}

// W [K][N] fp32 -> Wt [Npad][K] bf16 (rows >= N zero-filled)
__global__ void cvt_wt_kernel(const float* __restrict__ W, unsigned short* __restrict__ Wt,
                              int K, int N, int Npad) {
  int idx = blockIdx.x * 256 + threadIdx.x;
  if (idx >= Npad * K) return;
  int n = idx / K, k = idx % K;
  Wt[idx] = (n < N) ? f2bf(W[(long)k * N + n]) : (unsigned short)0;
}

// W [64][N] fp32 -> Wt [64][128] bf16 with K duplicated: Wt[n][k] = W[k&63][n]
// (B operand for hi/lo-decomposed za: sum_k (hi_k + lo_k) * W)
__global__ void cvt_wt_dup_kernel(const float* __restrict__ W, unsigned short* __restrict__ Wt,
                                  int N) {
  int idx = blockIdx.x * 256 + threadIdx.x;
  if (idx >= 64 * 128) return;
  int n = idx >> 7, k = idx & 127;
  Wt[idx] = (n < N) ? f2bf(W[(long)(k & 63) * N + n]) : (unsigned short)0;
}

__global__ void norms_kernel(const int* __restrict__ hist,
                             float* __restrict__ nsrc, float* __restrict__ ndst) {
  int i = blockIdx.x * 256 + threadIdx.x;
  if (i >= M_PAD) return;
  if (i < N_NODES) {
    nsrc[i] = rsqrtf(fmaxf((float)hist[N_NODES + i], 1.f));  // deg_out
    ndst[i] = rsqrtf(fmaxf((float)hist[i], 1.f));            // deg_in
  } else {
    nsrc[i] = 1.f;
  }
}

// ---------------- GEMM: C = A(bf16,[M_PAD][K]) x Bt(bf16,[Nfull][K])^T ----------------
// EPI 0: bf16( relu(acc + bias[col]) )
// EPI 1: bf16( relu(acc + bias[col]) * rowscale[row] )
// EPI 4: f32 relu(acc + bias[col]) -> out[row][col], row<N_NODES, col<40 (final layer)
// EDGES: blocks with blockIdx.x == gridDim.x-1 build adjacency buckets + degree
//        histograms, SHARDED by node range: group g = blockIdx.y%8 handles only
//        src/dst in [g*12500,(g+1)*12500). Each group re-scans all edges (streaming,
//        cheap) but its atomic+store working set (50 KB hist + 3.2 MB bucket slice)
//        stays L2-resident on one XCD -> no cross-XCD line migration.
// TPB=512 uses 8 waves in a 2(M)x4(N) arrangement; TPB=256 uses 2x2.
template <int BM, int BN, int BK, int EPI, bool EDGES, int TPB>
__launch_bounds__(TPB)
__global__ void gemm_bt(const unsigned short* __restrict__ A,
                        const unsigned short* __restrict__ Bt,
                        const float* __restrict__ bias,
                        const float* __restrict__ rowscale,
                        void* __restrict__ C, int K, int Nfull,
                        const int* __restrict__ esrc, const int* __restrict__ edst,
                        int* __restrict__ hist, int* __restrict__ bucket) {
  if constexpr (EDGES) {
    if (blockIdx.x == gridDim.x - 1) {
      const int grp = blockIdx.y & 7;
      const int member = blockIdx.y >> 3;
      const int members = (int)((gridDim.y - grp + 7) >> 3);   // blocks in this group
      const int lo = grp * (N_NODES / 8);
      const int hi = (grp == 7) ? N_NODES : lo + (N_NODES / 8);
      const int S = members * TPB;
      for (int e = member * TPB + (int)threadIdx.x; e < N_EDGES; e += S) {
        int s = esrc[e], d = edst[e];
        if (s >= lo && s < hi) atomicAdd(&hist[N_NODES + s], 1);
        if (d >= lo && d < hi) {
          int p = atomicAdd(&hist[d], 1);
          if (p < BCAP) bucket[(size_t)d * BCAP + p] = s;
        }
      }
      return;
    }
  }
  constexpr int WAVES = TPB / 64;
  constexpr int WAVES_M = 2, WAVES_N = WAVES / 2;  // 2x2 (TPB=256) or 2x4 (TPB=512)
  constexpr int WM = BM / WAVES_M, WN = BN / WAVES_N;
  constexpr int MI = WM / 16, NI = WN / 16;
  __shared__ __align__(16) unsigned short As[BM * BK];
  __shared__ __align__(16) unsigned short Bs[BN * BK];
  const int tid = threadIdx.x;
  const int wave = tid >> 6, lane = tid & 63;
  const int wm0 = (wave / WAVES_N) * WM, wn0 = (wave % WAVES_N) * WN;
  const long rowBase = (long)blockIdx.y * BM;
  const int colBase = blockIdx.x * BN;
  const unsigned short* Ab = A + rowBase * K;
  const unsigned short* Bb = Bt + (long)colBase * K;
  f32x4 acc[MI][NI] = {};
  constexpr int ACH = BM * BK / 8;  // 16B chunks
  constexpr int BCH = BN * BK / 8;
  for (int k0 = 0; k0 < K; k0 += BK) {
#pragma unroll
    for (int c = tid; c < ACH; c += TPB) {
      int r = (c * 8) / BK, cc = (c * 8) % BK;
      async_copy16(Ab + (long)r * K + k0 + cc, &As[c * 8]);
    }
#pragma unroll
    for (int c = tid; c < BCH; c += TPB) {
      int r = (c * 8) / BK, cc = (c * 8) % BK;
      async_copy16(Bb + (long)r * K + k0 + cc, &Bs[c * 8]);
    }
    __syncthreads();
#pragma unroll
    for (int kk = 0; kk < BK; kk += 32) {
      bf16x8 af[MI], bfr[NI];
#pragma unroll
      for (int mi = 0; mi < MI; ++mi)
        af[mi] = *(const bf16x8*)&As[(wm0 + mi * 16 + (lane & 15)) * BK + kk + (lane >> 4) * 8];
#pragma unroll
      for (int ni = 0; ni < NI; ++ni)
        bfr[ni] = *(const bf16x8*)&Bs[(wn0 + ni * 16 + (lane & 15)) * BK + kk + (lane >> 4) * 8];
#pragma unroll
      for (int mi = 0; mi < MI; ++mi)
#pragma unroll
        for (int ni = 0; ni < NI; ++ni)
          acc[mi][ni] = __builtin_amdgcn_mfma_f32_16x16x32_bf16(af[mi], bfr[ni], acc[mi][ni], 0, 0, 0);
    }
    __syncthreads();
  }
  const int q = lane >> 4, c15 = lane & 15;
#pragma unroll
  for (int mi = 0; mi < MI; ++mi) {
#pragma unroll
    for (int ni = 0; ni < NI; ++ni) {
#pragma unroll
      for (int r = 0; r < 4; ++r) {
        long row = rowBase + wm0 + mi * 16 + q * 4 + r;
        int col = colBase + wn0 + ni * 16 + c15;
        float v = acc[mi][ni][r];
        if constexpr (EPI == 0) {
          v = fmaxf(v + bias[col], 0.f);
          ((unsigned short*)C)[row * Nfull + col] = f2bf(v);
        } else if constexpr (EPI == 1) {
          v = fmaxf(v + bias[col], 0.f) * rowscale[row];
          ((unsigned short*)C)[row * Nfull + col] = f2bf(v);
        } else {  // EPI == 4: final layer f32 out [N_NODES][40]
          float bv = (col < 40) ? bias[col] : 0.f;
          float vv = fmaxf(v + bv, 0.f);
          if (row < N_NODES && col < 40)
            ((float*)C)[row * 40 + col] = vv;
        }
      }
    }
  }
}

// ---------------- aggregation over bf16 u-rows (aggregate-first order) -------------
// za[node][0:64]  = bf16_hi( ndst[node] * sum_{s in bucket[node]} u[s][:] )
// za[node][64:128]= bf16_lo( residual )          (K=128 GEMM vs dup-W gives ~f32)
// One node per 64-lane wave (4 nodes/block, no LDS -> high TLP).
// 8-way neighbor ILP: lane = slot*8 + colgrp; each lane covers 8 bf16 cols (16 B).
__global__ void agg_kernel(const unsigned short* __restrict__ u,
                           const int* __restrict__ bucket, const int* __restrict__ cnt,
                           const float* __restrict__ ndst,
                           unsigned short* __restrict__ za) {
  const int node = blockIdx.x * 4 + (threadIdx.x >> 6);
  const int lane = threadIdx.x & 63;
  const int r8 = lane >> 3;          // 0..7 neighbor slot
  const int c8 = (lane & 7) * 8;     // bf16 column start
  float a0 = 0.f, a1 = 0.f, a2 = 0.f, a3 = 0.f, a4 = 0.f, a5 = 0.f, a6 = 0.f, a7 = 0.f;
  int n = 0;
  if (node < N_NODES) n = min(cnt[node], BCAP);
  const int* bk = bucket + (size_t)node * BCAP;
#pragma unroll 2
  for (int i = r8; i < n; i += 8) {
    int s = bk[i];
    u16x8 v = *(const u16x8*)(u + (size_t)s * 64 + c8);
    a0 += bf2f(v[0]); a1 += bf2f(v[1]); a2 += bf2f(v[2]); a3 += bf2f(v[3]);
    a4 += bf2f(v[4]); a5 += bf2f(v[5]); a6 += bf2f(v[6]); a7 += bf2f(v[7]);
  }
#pragma unroll
  for (int m = 8; m <= 32; m <<= 1) {
    a0 += __shfl_xor(a0, m); a1 += __shfl_xor(a1, m);
    a2 += __shfl_xor(a2, m); a3 += __shfl_xor(a3, m);
    a4 += __shfl_xor(a4, m); a5 += __shfl_xor(a5, m);
    a6 += __shfl_xor(a6, m); a7 += __shfl_xor(a7, m);
  }
  if (r8 == 0) {
    float nd = (node < N_NODES) ? ndst[node] : 0.f;   // padded rows -> za = 0
    float vv[8] = {nd * a0, nd * a1, nd * a2, nd * a3, nd * a4, nd * a5, nd * a6, nd * a7};
    u16x8 H, L;
#pragma unroll
    for (int t = 0; t < 8; ++t) {
      unsigned short h = f2bf(vv[t]);
      H[t] = h;
      L[t] = f2bf(vv[t] - bf2f(h));
    }
    *(u16x8*)(za + (size_t)node * 128 + c8) = H;
    *(u16x8*)(za + (size_t)node * 128 + 64 + c8) = L;
  }
}

// ---------------- launch ----------------

extern "C" void kernel_launch(void* const* d_in, const int* in_sizes, int n_in,
                              void* d_out, int out_size, void* d_ws, size_t ws_size,
                              hipStream_t stream) {
  (void)in_sizes; (void)n_in; (void)out_size; (void)ws_size;
  const float* x   = (const float*)d_in[0];
  const int* esrc  = (const int*)d_in[1];
  const int* edst  = (const int*)d_in[2];
  const float* W1  = (const float*)d_in[3];  const float* b1  = (const float*)d_in[4];
  const float* W2  = (const float*)d_in[5];  const float* b2  = (const float*)d_in[6];
  const float* W3  = (const float*)d_in[7];  const float* b3  = (const float*)d_in[8];
  const float* Wg1 = (const float*)d_in[9];  const float* bg1 = (const float*)d_in[10];
  const float* Wg2 = (const float*)d_in[11]; const float* bg2 = (const float*)d_in[12];
  const float* Wg3 = (const float*)d_in[13]; const float* bg3 = (const float*)d_in[14];
  const float* Wg4 = (const float*)d_in[15]; const float* bg4 = (const float*)d_in[16];
  float* out = (float*)d_out;

  char* ws = (char*)d_ws;
  size_t off = 0;
  auto alloc = [&](size_t bytes) -> void* {
    void* p = ws + off;
    off += (bytes + 255) & ~(size_t)255;
    return p;
  };

  unsigned short* xb = (unsigned short*)alloc((size_t)M_PAD * 512 * 2);  // region0 (reused)
  unsigned short* h1 = (unsigned short*)alloc((size_t)M_PAD * 512 * 2);
  int*   bucket  = (int*)alloc((size_t)N_NODES * BCAP * 4);
  int*   hist    = (int*)alloc((size_t)2 * N_NODES * 4);
  float* nsrc    = (float*)alloc((size_t)M_PAD * 4);
  float* ndst    = (float*)alloc((size_t)N_NODES * 4);
  unsigned short* W1t  = (unsigned short*)alloc(512 * 512 * 2);
  unsigned short* W2t  = (unsigned short*)alloc(256 * 512 * 2);
  unsigned short* W3t  = (unsigned short*)alloc(64 * 256 * 2);
  unsigned short* Wg1t = (unsigned short*)alloc(64 * 128 * 2);   // dup-K layout
  unsigned short* Wg2t = (unsigned short*)alloc(64 * 128 * 2);
  unsigned short* Wg3t = (unsigned short*)alloc(64 * 128 * 2);
  unsigned short* Wg4t = (unsigned short*)alloc(64 * 128 * 2);

  // region0 reuse (xb dead after layer-1 GEMM); h2+U0+U1+za = M_PAD*512*2 B exactly:
  unsigned short* h2 = xb;                                                      // M_PAD*256 bf16
  unsigned short* U0 = (unsigned short*)((char*)xb + (size_t)M_PAD * 256 * 2);  // M_PAD*64 bf16
  unsigned short* U1 = (unsigned short*)((char*)U0 + (size_t)M_PAD * 64 * 2);   // M_PAD*64 bf16
  unsigned short* za = (unsigned short*)((char*)U1 + (size_t)M_PAD * 64 * 2);   // M_PAD*128 bf16

  // 1) zero both histograms — exact size
  hipMemsetAsync(hist, 0, (size_t)2 * N_NODES * 4, stream);

  // 2) x -> bf16 padded
  cvt_x_kernel<<<(int)(X_PAD / 8 / 256), 256, 0, stream>>>(x, xb);

  // 3) weights -> bf16 transposed [Npad][K]; GCN weights in dup-K [64][128]
  cvt_wt_kernel<<<(512 * 512 + 255) / 256, 256, 0, stream>>>(W1, W1t, 512, 512, 512);
  cvt_wt_kernel<<<(256 * 512 + 255) / 256, 256, 0, stream>>>(W2, W2t, 512, 256, 256);
  cvt_wt_kernel<<<(64 * 256 + 255) / 256, 256, 0, stream>>>(W3, W3t, 256, 64, 64);
  cvt_wt_dup_kernel<<<(64 * 128 + 255) / 256, 256, 0, stream>>>(Wg1, Wg1t, 64);
  cvt_wt_dup_kernel<<<(64 * 128 + 255) / 256, 256, 0, stream>>>(Wg2, Wg2t, 64);
  cvt_wt_dup_kernel<<<(64 * 128 + 255) / 256, 256, 0, stream>>>(Wg3, Wg3t, 64);
  cvt_wt_dup_kernel<<<(64 * 128 + 255) / 256, 256, 0, stream>>>(Wg4, Wg4t, 40);  // pad 40->64

  const int GY = M_PAD / 128;  // 782

  // 4) GEMM1 (BN=256, 512 threads) fused with XCD-sharded edge-bucket build:
  //    x=0..1 GEMM cols, x=2 edge role (782 blocks, 8 node-range groups).
  gemm_bt<128, 256, 64, 0, true, 512><<<dim3(3, GY), 512, 0, stream>>>(
      xb, W1t, b1, nullptr, h1, 512, 512, esrc, edst, hist, bucket);

  // 5) norms (hist complete after fused dispatch)
  norms_kernel<<<(M_PAD + 255) / 256, 256, 0, stream>>>(hist, nsrc, ndst);

  // 6) rest of MLP (GEMM2 BN=256: h1 read once)
  gemm_bt<128, 256, 64, 0, false, 512><<<dim3(1, GY), 512, 0, stream>>>(
      h1, W2t, b2, nullptr, h2, 512, 256, nullptr, nullptr, nullptr, nullptr);
  gemm_bt<128, 64, 64, 1, false, 256><<<dim3(1, GY), 256, 0, stream>>>(
      h2, W3t, b3, nsrc, U0, 256, 64, nullptr, nullptr, nullptr, nullptr);

  // 7) GCN layers, aggregate-first: za = hi/lo(ndst * segsum(u)); u' = epilogue(za @ Wdup)
  agg_kernel<<<M_PAD / 4, 256, 0, stream>>>(U0, bucket, hist, ndst, za);
  gemm_bt<128, 64, 64, 1, false, 256><<<dim3(1, GY), 256, 0, stream>>>(
      za, Wg1t, bg1, nsrc, U1, 128, 64, nullptr, nullptr, nullptr, nullptr);

  agg_kernel<<<M_PAD / 4, 256, 0, stream>>>(U1, bucket, hist, ndst, za);
  gemm_bt<128, 64, 64, 1, false, 256><<<dim3(1, GY), 256, 0, stream>>>(
      za, Wg2t, bg2, nsrc, U0, 128, 64, nullptr, nullptr, nullptr, nullptr);

  agg_kernel<<<M_PAD / 4, 256, 0, stream>>>(U0, bucket, hist, ndst, za);
  gemm_bt<128, 64, 64, 1, false, 256><<<dim3(1, GY), 256, 0, stream>>>(
      za, Wg3t, bg3, nsrc, U1, 128, 64, nullptr, nullptr, nullptr, nullptr);

  agg_kernel<<<M_PAD / 4, 256, 0, stream>>>(U1, bucket, hist, ndst, za);
  gemm_bt<128, 64, 64, 4, false, 256><<<dim3(1, GY), 256, 0, stream>>>(
      za, Wg4t, bg4, nullptr, out, 128, 64, nullptr, nullptr, nullptr, nullptr);
}

// Round 8
// 825.987 us; speedup vs baseline: 1.1823x; 1.0173x over previous
//
#include <hip/hip_runtime.h>

#define N_NODES 100000
#define N_EDGES 1600000
#define M_PAD   100096   // 782 * 128
#define BCAP    64       // bucket capacity per node (Poisson(16): P(>=64) ~ 1e-20)
#define EBLK    96       // edge-role blocks: enough to saturate L3 atomic RMW units,
                         // few enough to not crowd GEMM block slots (48KB LDS each)
#define X_REAL 51200000L          // N_NODES*512
#define X_PAD  ((long)M_PAD*512)  // 51249152, divisible by 2048

typedef __bf16 bf16x8 __attribute__((ext_vector_type(8)));
typedef float  f32x4  __attribute__((ext_vector_type(4)));
typedef unsigned short u16x8 __attribute__((ext_vector_type(8)));

__device__ __forceinline__ unsigned short f2bf(float f) {
  union { float f; unsigned u; } x; x.f = f;
  unsigned r = (x.u + 0x7FFFu + ((x.u >> 16) & 1u)) >> 16;
  return (unsigned short)r;
}

__device__ __forceinline__ float bf2f(unsigned short h) {
  union { unsigned u; float f; } x; x.u = ((unsigned)h) << 16;
  return x.f;
}

__device__ __forceinline__ void async_copy16(const void* g, void* l) {
  __builtin_amdgcn_global_load_lds((__attribute__((address_space(1))) void*)g,
                                   (__attribute__((address_space(3))) void*)l,
                                   16, 0, 0);
}

// ---------------- prep kernels ----------------

__global__ void cvt_x_kernel(const float* __restrict__ x, unsigned short* __restrict__ xb) {
  long e = ((long)blockIdx.x * 256 + threadIdx.x) * 8;   // grid sized exactly: X_PAD/8/256 blocks
  u16x8 o;
  if (e < X_REAL) {
    float4 f0 = *(const float4*)(x + e);
    float4 f1 = *(const float4*)(x + e + 4);
    o[0] = f2bf(f0.x); o[1] = f2bf(f0.y); o[2] = f2bf(f0.z); o[3] = f2bf(f0.w);
    o[4] = f2bf(f1.x); o[5] = f2bf(f1.y); o[6] = f2bf(f1.z); o[7] = f2bf(f1.w);
  } else {
    o = (u16x8)0;
  }
  *(u16x8*)(xb + e) = o;
}

// W [K][N] fp32 -> Wt [Npad][K] bf16 (rows >= N zero-filled)
__global__ void cvt_wt_kernel(const float* __restrict__ W, unsigned short* __restrict__ Wt,
                              int K, int N, int Npad) {
  int idx = blockIdx.x * 256 + threadIdx.x;
  if (idx >= Npad * K) return;
  int n = idx / K, k = idx % K;
  Wt[idx] = (n < N) ? f2bf(W[(long)k * N + n]) : (unsigned short)0;
}

// W [64][N] fp32 -> Wt [64][128] bf16 with K duplicated: Wt[n][k] = W[k&63][n]
// (B operand for hi/lo-decomposed za: sum_k (hi_k + lo_k) * W)
__global__ void cvt_wt_dup_kernel(const float* __restrict__ W, unsigned short* __restrict__ Wt,
                                  int N) {
  int idx = blockIdx.x * 256 + threadIdx.x;
  if (idx >= 64 * 128) return;
  int n = idx >> 7, k = idx & 127;
  Wt[idx] = (n < N) ? f2bf(W[(long)(k & 63) * N + n]) : (unsigned short)0;
}

__global__ void norms_kernel(const int* __restrict__ hist,
                             float* __restrict__ nsrc, float* __restrict__ ndst) {
  int i = blockIdx.x * 256 + threadIdx.x;
  if (i >= M_PAD) return;
  if (i < N_NODES) {
    nsrc[i] = rsqrtf(fmaxf((float)hist[N_NODES + i], 1.f));  // deg_out
    ndst[i] = rsqrtf(fmaxf((float)hist[i], 1.f));            // deg_in
  } else {
    nsrc[i] = 1.f;
  }
}

// ---------------- GEMM: C = A(bf16,[M_PAD][K]) x Bt(bf16,[Nfull][K])^T ----------------
// EPI 0: bf16( relu(acc + bias[col]) )
// EPI 1: bf16( relu(acc + bias[col]) * rowscale[row] )
// EPI 4: f32 relu(acc + bias[col]) -> out[row][col], row<N_NODES, col<40 (final layer)
// EDGES: blocks with blockIdx.x == gridDim.x-1 and blockIdx.y < EBLK build the
//        adjacency buckets + degree histograms for ALL edges (4-edge batched for
//        atomic ILP). y >= EBLK returns immediately -> frees its LDS/block slot so
//        GEMM keeps ~full block-level parallelism while the small atomic-bound
//        role saturates the L3 RMW units from ~4% of the slots.
// TPB=512 uses 8 waves in a 2(M)x4(N) arrangement; TPB=256 uses 2x2.
template <int BM, int BN, int BK, int EPI, bool EDGES, int TPB>
__launch_bounds__(TPB)
__global__ void gemm_bt(const unsigned short* __restrict__ A,
                        const unsigned short* __restrict__ Bt,
                        const float* __restrict__ bias,
                        const float* __restrict__ rowscale,
                        void* __restrict__ C, int K, int Nfull,
                        const int* __restrict__ esrc, const int* __restrict__ edst,
                        int* __restrict__ hist, int* __restrict__ bucket) {
  if constexpr (EDGES) {
    if (blockIdx.x == gridDim.x - 1) {
      if (blockIdx.y >= EBLK) return;   // free the slot immediately
      const int S = EBLK * TPB;
      int e = blockIdx.y * TPB + (int)threadIdx.x;
      for (; e + 3 * S < N_EDGES; e += 4 * S) {
        int s0 = esrc[e],         d0 = edst[e];
        int s1 = esrc[e + S],     d1 = edst[e + S];
        int s2 = esrc[e + 2 * S], d2 = edst[e + 2 * S];
        int s3 = esrc[e + 3 * S], d3 = edst[e + 3 * S];
        atomicAdd(&hist[N_NODES + s0], 1);  // no-return atomics: fire-and-forget
        atomicAdd(&hist[N_NODES + s1], 1);
        atomicAdd(&hist[N_NODES + s2], 1);
        atomicAdd(&hist[N_NODES + s3], 1);
        int p0 = atomicAdd(&hist[d0], 1);   // 4 independent returning atomics in flight
        int p1 = atomicAdd(&hist[d1], 1);
        int p2 = atomicAdd(&hist[d2], 1);
        int p3 = atomicAdd(&hist[d3], 1);
        if (p0 < BCAP) bucket[(size_t)d0 * BCAP + p0] = s0;
        if (p1 < BCAP) bucket[(size_t)d1 * BCAP + p1] = s1;
        if (p2 < BCAP) bucket[(size_t)d2 * BCAP + p2] = s2;
        if (p3 < BCAP) bucket[(size_t)d3 * BCAP + p3] = s3;
      }
      for (; e < N_EDGES; e += S) {
        int s = esrc[e], d = edst[e];
        atomicAdd(&hist[N_NODES + s], 1);
        int p = atomicAdd(&hist[d], 1);
        if (p < BCAP) bucket[(size_t)d * BCAP + p] = s;
      }
      return;
    }
  }
  constexpr int WAVES = TPB / 64;
  constexpr int WAVES_M = 2, WAVES_N = WAVES / 2;  // 2x2 (TPB=256) or 2x4 (TPB=512)
  constexpr int WM = BM / WAVES_M, WN = BN / WAVES_N;
  constexpr int MI = WM / 16, NI = WN / 16;
  __shared__ __align__(16) unsigned short As[BM * BK];
  __shared__ __align__(16) unsigned short Bs[BN * BK];
  const int tid = threadIdx.x;
  const int wave = tid >> 6, lane = tid & 63;
  const int wm0 = (wave / WAVES_N) * WM, wn0 = (wave % WAVES_N) * WN;
  const long rowBase = (long)blockIdx.y * BM;
  const int colBase = blockIdx.x * BN;
  const unsigned short* Ab = A + rowBase * K;
  const unsigned short* Bb = Bt + (long)colBase * K;
  f32x4 acc[MI][NI] = {};
  constexpr int ACH = BM * BK / 8;  // 16B chunks
  constexpr int BCH = BN * BK / 8;
  for (int k0 = 0; k0 < K; k0 += BK) {
#pragma unroll
    for (int c = tid; c < ACH; c += TPB) {
      int r = (c * 8) / BK, cc = (c * 8) % BK;
      async_copy16(Ab + (long)r * K + k0 + cc, &As[c * 8]);
    }
#pragma unroll
    for (int c = tid; c < BCH; c += TPB) {
      int r = (c * 8) / BK, cc = (c * 8) % BK;
      async_copy16(Bb + (long)r * K + k0 + cc, &Bs[c * 8]);
    }
    __syncthreads();
#pragma unroll
    for (int kk = 0; kk < BK; kk += 32) {
      bf16x8 af[MI], bfr[NI];
#pragma unroll
      for (int mi = 0; mi < MI; ++mi)
        af[mi] = *(const bf16x8*)&As[(wm0 + mi * 16 + (lane & 15)) * BK + kk + (lane >> 4) * 8];
#pragma unroll
      for (int ni = 0; ni < NI; ++ni)
        bfr[ni] = *(const bf16x8*)&Bs[(wn0 + ni * 16 + (lane & 15)) * BK + kk + (lane >> 4) * 8];
#pragma unroll
      for (int mi = 0; mi < MI; ++mi)
#pragma unroll
        for (int ni = 0; ni < NI; ++ni)
          acc[mi][ni] = __builtin_amdgcn_mfma_f32_16x16x32_bf16(af[mi], bfr[ni], acc[mi][ni], 0, 0, 0);
    }
    __syncthreads();
  }
  const int q = lane >> 4, c15 = lane & 15;
#pragma unroll
  for (int mi = 0; mi < MI; ++mi) {
#pragma unroll
    for (int ni = 0; ni < NI; ++ni) {
#pragma unroll
      for (int r = 0; r < 4; ++r) {
        long row = rowBase + wm0 + mi * 16 + q * 4 + r;
        int col = colBase + wn0 + ni * 16 + c15;
        float v = acc[mi][ni][r];
        if constexpr (EPI == 0) {
          v = fmaxf(v + bias[col], 0.f);
          ((unsigned short*)C)[row * Nfull + col] = f2bf(v);
        } else if constexpr (EPI == 1) {
          v = fmaxf(v + bias[col], 0.f) * rowscale[row];
          ((unsigned short*)C)[row * Nfull + col] = f2bf(v);
        } else {  // EPI == 4: final layer f32 out [N_NODES][40]
          float bv = (col < 40) ? bias[col] : 0.f;
          float vv = fmaxf(v + bv, 0.f);
          if (row < N_NODES && col < 40)
            ((float*)C)[row * 40 + col] = vv;
        }
      }
    }
  }
}

// ---------------- aggregation over bf16 u-rows (aggregate-first order) -------------
// za[node][0:64]  = bf16_hi( ndst[node] * sum_{s in bucket[node]} u[s][:] )
// za[node][64:128]= bf16_lo( residual )          (K=128 GEMM vs dup-W gives ~f32)
// One node per 64-lane wave (4 nodes/block, no LDS -> high TLP).
// 8-way neighbor ILP: lane = slot*8 + colgrp; each lane covers 8 bf16 cols (16 B).
__global__ void agg_kernel(const unsigned short* __restrict__ u,
                           const int* __restrict__ bucket, const int* __restrict__ cnt,
                           const float* __restrict__ ndst,
                           unsigned short* __restrict__ za) {
  const int node = blockIdx.x * 4 + (threadIdx.x >> 6);
  const int lane = threadIdx.x & 63;
  const int r8 = lane >> 3;          // 0..7 neighbor slot
  const int c8 = (lane & 7) * 8;     // bf16 column start
  float a0 = 0.f, a1 = 0.f, a2 = 0.f, a3 = 0.f, a4 = 0.f, a5 = 0.f, a6 = 0.f, a7 = 0.f;
  int n = 0;
  if (node < N_NODES) n = min(cnt[node], BCAP);
  const int* bk = bucket + (size_t)node * BCAP;
#pragma unroll 2
  for (int i = r8; i < n; i += 8) {
    int s = bk[i];
    u16x8 v = *(const u16x8*)(u + (size_t)s * 64 + c8);
    a0 += bf2f(v[0]); a1 += bf2f(v[1]); a2 += bf2f(v[2]); a3 += bf2f(v[3]);
    a4 += bf2f(v[4]); a5 += bf2f(v[5]); a6 += bf2f(v[6]); a7 += bf2f(v[7]);
  }
#pragma unroll
  for (int m = 8; m <= 32; m <<= 1) {
    a0 += __shfl_xor(a0, m); a1 += __shfl_xor(a1, m);
    a2 += __shfl_xor(a2, m); a3 += __shfl_xor(a3, m);
    a4 += __shfl_xor(a4, m); a5 += __shfl_xor(a5, m);
    a6 += __shfl_xor(a6, m); a7 += __shfl_xor(a7, m);
  }
  if (r8 == 0) {
    float nd = (node < N_NODES) ? ndst[node] : 0.f;   // padded rows -> za = 0
    float vv[8] = {nd * a0, nd * a1, nd * a2, nd * a3, nd * a4, nd * a5, nd * a6, nd * a7};
    u16x8 H, L;
#pragma unroll
    for (int t = 0; t < 8; ++t) {
      unsigned short h = f2bf(vv[t]);
      H[t] = h;
      L[t] = f2bf(vv[t] - bf2f(h));
    }
    *(u16x8*)(za + (size_t)node * 128 + c8) = H;
    *(u16x8*)(za + (size_t)node * 128 + 64 + c8) = L;
  }
}

// ---------------- launch ----------------

extern "C" void kernel_launch(void* const* d_in, const int* in_sizes, int n_in,
                              void* d_out, int out_size, void* d_ws, size_t ws_size,
                              hipStream_t stream) {
  (void)in_sizes; (void)n_in; (void)out_size; (void)ws_size;
  const float* x   = (const float*)d_in[0];
  const int* esrc  = (const int*)d_in[1];
  const int* edst  = (const int*)d_in[2];
  const float* W1  = (const float*)d_in[3];  const float* b1  = (const float*)d_in[4];
  const float* W2  = (const float*)d_in[5];  const float* b2  = (const float*)d_in[6];
  const float* W3  = (const float*)d_in[7];  const float* b3  = (const float*)d_in[8];
  const float* Wg1 = (const float*)d_in[9];  const float* bg1 = (const float*)d_in[10];
  const float* Wg2 = (const float*)d_in[11]; const float* bg2 = (const float*)d_in[12];
  const float* Wg3 = (const float*)d_in[13]; const float* bg3 = (const float*)d_in[14];
  const float* Wg4 = (const float*)d_in[15]; const float* bg4 = (const float*)d_in[16];
  float* out = (float*)d_out;

  char* ws = (char*)d_ws;
  size_t off = 0;
  auto alloc = [&](size_t bytes) -> void* {
    void* p = ws + off;
    off += (bytes + 255) & ~(size_t)255;
    return p;
  };

  unsigned short* xb = (unsigned short*)alloc((size_t)M_PAD * 512 * 2);  // region0 (reused)
  unsigned short* h1 = (unsigned short*)alloc((size_t)M_PAD * 512 * 2);
  int*   bucket  = (int*)alloc((size_t)N_NODES * BCAP * 4);
  int*   hist    = (int*)alloc((size_t)2 * N_NODES * 4);
  float* nsrc    = (float*)alloc((size_t)M_PAD * 4);
  float* ndst    = (float*)alloc((size_t)N_NODES * 4);
  unsigned short* W1t  = (unsigned short*)alloc(512 * 512 * 2);
  unsigned short* W2t  = (unsigned short*)alloc(256 * 512 * 2);
  unsigned short* W3t  = (unsigned short*)alloc(64 * 256 * 2);
  unsigned short* Wg1t = (unsigned short*)alloc(64 * 128 * 2);   // dup-K layout
  unsigned short* Wg2t = (unsigned short*)alloc(64 * 128 * 2);
  unsigned short* Wg3t = (unsigned short*)alloc(64 * 128 * 2);
  unsigned short* Wg4t = (unsigned short*)alloc(64 * 128 * 2);

  // region0 reuse (xb dead after layer-1 GEMM); h2+U0+U1+za = M_PAD*512*2 B exactly:
  unsigned short* h2 = xb;                                                      // M_PAD*256 bf16
  unsigned short* U0 = (unsigned short*)((char*)xb + (size_t)M_PAD * 256 * 2);  // M_PAD*64 bf16
  unsigned short* U1 = (unsigned short*)((char*)U0 + (size_t)M_PAD * 64 * 2);   // M_PAD*64 bf16
  unsigned short* za = (unsigned short*)((char*)U1 + (size_t)M_PAD * 64 * 2);   // M_PAD*128 bf16

  // 1) zero both histograms — exact size
  hipMemsetAsync(hist, 0, (size_t)2 * N_NODES * 4, stream);

  // 2) x -> bf16 padded
  cvt_x_kernel<<<(int)(X_PAD / 8 / 256), 256, 0, stream>>>(x, xb);

  // 3) weights -> bf16 transposed [Npad][K]; GCN weights in dup-K [64][128]
  cvt_wt_kernel<<<(512 * 512 + 255) / 256, 256, 0, stream>>>(W1, W1t, 512, 512, 512);
  cvt_wt_kernel<<<(256 * 512 + 255) / 256, 256, 0, stream>>>(W2, W2t, 512, 256, 256);
  cvt_wt_kernel<<<(64 * 256 + 255) / 256, 256, 0, stream>>>(W3, W3t, 256, 64, 64);
  cvt_wt_dup_kernel<<<(64 * 128 + 255) / 256, 256, 0, stream>>>(Wg1, Wg1t, 64);
  cvt_wt_dup_kernel<<<(64 * 128 + 255) / 256, 256, 0, stream>>>(Wg2, Wg2t, 64);
  cvt_wt_dup_kernel<<<(64 * 128 + 255) / 256, 256, 0, stream>>>(Wg3, Wg3t, 64);
  cvt_wt_dup_kernel<<<(64 * 128 + 255) / 256, 256, 0, stream>>>(Wg4, Wg4t, 40);  // pad 40->64

  const int GY = M_PAD / 128;  // 782

  // 4) GEMM1 (BN=256, 512 threads) fused with edge-bucket build (EBLK blocks):
  //    x=0..1 GEMM cols; x=2,y<EBLK edge role; x=2,y>=EBLK exit immediately.
  gemm_bt<128, 256, 64, 0, true, 512><<<dim3(3, GY), 512, 0, stream>>>(
      xb, W1t, b1, nullptr, h1, 512, 512, esrc, edst, hist, bucket);

  // 5) norms (hist complete after fused dispatch)
  norms_kernel<<<(M_PAD + 255) / 256, 256, 0, stream>>>(hist, nsrc, ndst);

  // 6) rest of MLP (GEMM2 BN=256: h1 read once)
  gemm_bt<128, 256, 64, 0, false, 512><<<dim3(1, GY), 512, 0, stream>>>(
      h1, W2t, b2, nullptr, h2, 512, 256, nullptr, nullptr, nullptr, nullptr);
  gemm_bt<128, 64, 64, 1, false, 256><<<dim3(1, GY), 256, 0, stream>>>(
      h2, W3t, b3, nsrc, U0, 256, 64, nullptr, nullptr, nullptr, nullptr);

  // 7) GCN layers, aggregate-first: za = hi/lo(ndst * segsum(u)); u' = epilogue(za @ Wdup)
  agg_kernel<<<M_PAD / 4, 256, 0, stream>>>(U0, bucket, hist, ndst, za);
  gemm_bt<128, 64, 64, 1, false, 256><<<dim3(1, GY), 256, 0, stream>>>(
      za, Wg1t, bg1, nsrc, U1, 128, 64, nullptr, nullptr, nullptr, nullptr);

  agg_kernel<<<M_PAD / 4, 256, 0, stream>>>(U1, bucket, hist, ndst, za);
  gemm_bt<128, 64, 64, 1, false, 256><<<dim3(1, GY), 256, 0, stream>>>(
      za, Wg2t, bg2, nsrc, U0, 128, 64, nullptr, nullptr, nullptr, nullptr);

  agg_kernel<<<M_PAD / 4, 256, 0, stream>>>(U0, bucket, hist, ndst, za);
  gemm_bt<128, 64, 64, 1, false, 256><<<dim3(1, GY), 256, 0, stream>>>(
      za, Wg3t, bg3, nsrc, U1, 128, 64, nullptr, nullptr, nullptr, nullptr);

  agg_kernel<<<M_PAD / 4, 256, 0, stream>>>(U1, bucket, hist, ndst, za);
  gemm_bt<128, 64, 64, 4, false, 256><<<dim3(1, GY), 256, 0, stream>>>(
      za, Wg4t, bg4, nullptr, out, 128, 64, nullptr, nullptr, nullptr, nullptr);
}